// Round 3
// baseline (455.079 us; speedup 1.0000x reference)
//
#include <hip/hip_runtime.h>
#include <hip/hip_bf16.h>

#define IN_CH 128
#define OUT_CH 64

// ---------------- degree count ----------------
__global__ void count_kernel(const int* __restrict__ col, int* __restrict__ cnt, int E) {
    int e = blockIdx.x * blockDim.x + threadIdx.x;
    if (e < E) atomicAdd(&cnt[col[e]], 1);
}

// ---------------- 3-phase parallel exclusive scan ----------------
__global__ void __launch_bounds__(256) partial_kernel(const int* __restrict__ cnt,
                                                      int* __restrict__ bsum, int n) {
    __shared__ int red[256];
    int tid = threadIdx.x;
    int i = blockIdx.x * 256 + tid;
    red[tid] = (i < n) ? cnt[i] : 0;
    __syncthreads();
    for (int d = 128; d > 0; d >>= 1) {
        if (tid < d) red[tid] += red[tid + d];
        __syncthreads();
    }
    if (tid == 0) bsum[blockIdx.x] = red[0];
}

__global__ void __launch_bounds__(256) scansums_kernel(int* __restrict__ bsum, int nb) {
    __shared__ int ps[256];
    int tid = threadIdx.x;
    int v = (tid < nb) ? bsum[tid] : 0;
    ps[tid] = v;
    __syncthreads();
    for (int d = 1; d < 256; d <<= 1) {
        int t = 0;
        if (tid >= d) t = ps[tid - d];
        __syncthreads();
        if (tid >= d) ps[tid] += t;
        __syncthreads();
    }
    if (tid < nb) bsum[tid] = ps[tid] - v;   // exclusive
}

__global__ void __launch_bounds__(256) scanwrite_kernel(const int* __restrict__ cnt,
                                                        const int* __restrict__ bsum,
                                                        int* __restrict__ off,
                                                        int* __restrict__ pos,
                                                        float* __restrict__ dis, int n) {
    __shared__ int ps[256];
    int tid = threadIdx.x;
    int i = blockIdx.x * 256 + tid;
    int c = (i < n) ? cnt[i] : 0;
    ps[tid] = c;
    __syncthreads();
    for (int d = 1; d < 256; d <<= 1) {
        int t = 0;
        if (tid >= d) t = ps[tid - d];
        __syncthreads();
        if (tid >= d) ps[tid] += t;
        __syncthreads();
    }
    int excl = ps[tid] - c + bsum[blockIdx.x];
    if (i < n) {
        off[i] = excl;
        pos[i] = excl;
        dis[i] = rsqrtf((float)(c + 1));   // +1 self-loop, matches gcn_norm
        if (i == n - 1) off[n] = excl + c;
    }
}

// ---------------- scatter edges into CSR order, pack (row, norm) ----------------
__global__ void scatter_kernel(const int* __restrict__ row, const int* __restrict__ col,
                               const float* __restrict__ dis, int* __restrict__ pos,
                               int2* __restrict__ edges, int E) {
    int e = blockIdx.x * blockDim.x + threadIdx.x;
    if (e < E) {
        int r = row[e], c = col[e];
        int p = atomicAdd(&pos[c], 1);
        float nrm = dis[r] * dis[c];
        edges[p] = make_int2(r, __float_as_int(nrm));
    }
}

// ---------------- Y = X @ W^T : lane = node, W via scalar loads ----------------
// Each thread computes one node's 64 outputs. W indices are wave-uniform ->
// compiler emits s_load (scalar cache, scalar pipe) -> FMA is v_fma(vacc, vx, s_w).
// No LDS, ~110 VGPRs, purely VALU-bound.
__global__ void __launch_bounds__(256) gemm_kernel(const float* __restrict__ x,
                                                   const float* __restrict__ W,
                                                   float* __restrict__ y, int n) {
    int v = blockIdx.x * 256 + threadIdx.x;
    if (v >= n) return;
    const float4* xr = (const float4*)(x + (size_t)v * IN_CH);
    float acc[OUT_CH];
#pragma unroll
    for (int o = 0; o < OUT_CH; ++o) acc[o] = 0.f;
#pragma unroll
    for (int kc = 0; kc < IN_CH / 32; ++kc) {       // k in chunks of 32
        float4 xx[8];
#pragma unroll
        for (int j = 0; j < 8; ++j) xx[j] = xr[kc * 8 + j];
#pragma unroll
        for (int o = 0; o < OUT_CH; ++o) {
            const float4* Wo = (const float4*)(W + (size_t)o * IN_CH + kc * 32);
            float s = 0.f;
#pragma unroll
            for (int j = 0; j < 8; ++j) {
                float4 w = Wo[j];                    // wave-uniform -> s_load
                s += xx[j].x * w.x + xx[j].y * w.y + xx[j].z * w.z + xx[j].w * w.w;
            }
            acc[o] += s;
        }
    }
    float4* yr = (float4*)(y + (size_t)v * OUT_CH);
#pragma unroll
    for (int o = 0; o < OUT_CH / 4; ++o)
        yr[o] = make_float4(acc[4 * o], acc[4 * o + 1], acc[4 * o + 2], acc[4 * o + 3]);
}

// ---------------- one propagation hop: wave per node, lane = feature ----------------
template <bool FINAL>
__global__ void __launch_bounds__(256) hop_kernel(const float* __restrict__ yin,
                                                  float* __restrict__ yout,
                                                  const int2* __restrict__ edges,
                                                  const int* __restrict__ off,
                                                  const float* __restrict__ dis,
                                                  const float* __restrict__ bias, int n) {
    int wid = (blockIdx.x * 256 + threadIdx.x) >> 6;
    int lane = threadIdx.x & 63;
    if (wid >= n) return;
    int v = wid;
    int s = off[v], e = off[v + 1];
    float dv = dis[v];
    float acc = dv * dv * yin[(size_t)v * OUT_CH + lane];   // self-loop term
    int i = s;
    for (; i + 4 <= e; i += 4) {
        int2 e0 = edges[i], e1 = edges[i + 1], e2 = edges[i + 2], e3 = edges[i + 3];
        float y0 = yin[(size_t)e0.x * OUT_CH + lane];
        float y1 = yin[(size_t)e1.x * OUT_CH + lane];
        float y2 = yin[(size_t)e2.x * OUT_CH + lane];
        float y3 = yin[(size_t)e3.x * OUT_CH + lane];
        acc += __int_as_float(e0.y) * y0;
        acc += __int_as_float(e1.y) * y1;
        acc += __int_as_float(e2.y) * y2;
        acc += __int_as_float(e3.y) * y3;
    }
    for (; i < e; ++i) {
        int2 ed = edges[i];
        acc += __int_as_float(ed.y) * yin[(size_t)ed.x * OUT_CH + lane];
    }
    if (FINAL) acc += bias[lane];
    yout[(size_t)v * OUT_CH + lane] = acc;
}

extern "C" void kernel_launch(void* const* d_in, const int* in_sizes, int n_in,
                              void* d_out, int out_size, void* d_ws, size_t ws_size,
                              hipStream_t stream) {
    const float* x = (const float*)d_in[0];
    const int* ei = (const int*)d_in[1];
    const float* W = (const float*)d_in[2];
    const float* b = (const float*)d_in[3];
    int n = in_sizes[0] / IN_CH;   // 50000
    int E = in_sizes[1] / 2;       // 800000
    const int* row = ei;           // edge_index[0] = source
    const int* col = ei + E;       // edge_index[1] = target

    char* ws = (char*)d_ws;
    size_t o = 0;
    auto alloc = [&](size_t bytes) -> void* {
        void* p = ws + o;
        o += (bytes + 255) & ~(size_t)255;
        return p;
    };
    int*   cnt   = (int*)alloc((size_t)n * 4);
    int*   off   = (int*)alloc((size_t)(n + 1) * 4);
    int*   pos   = (int*)alloc((size_t)n * 4);
    float* dis   = (float*)alloc((size_t)n * 4);
    int2*  edges = (int2*)alloc((size_t)E * 8);
    float* yA    = (float*)alloc((size_t)n * OUT_CH * 4);
    float* yB    = (float*)alloc((size_t)n * OUT_CH * 4);
    int*   bsum  = (int*)alloc(1024 * 4);

    int nTiles = (n + 255) / 256;  // 196

    hipMemsetAsync(cnt, 0, (size_t)n * 4, stream);
    count_kernel<<<(E + 255) / 256, 256, 0, stream>>>(col, cnt, E);
    partial_kernel<<<nTiles, 256, 0, stream>>>(cnt, bsum, n);
    scansums_kernel<<<1, 256, 0, stream>>>(bsum, nTiles);
    scanwrite_kernel<<<nTiles, 256, 0, stream>>>(cnt, bsum, off, pos, dis, n);
    scatter_kernel<<<(E + 255) / 256, 256, 0, stream>>>(row, col, dis, pos, edges, E);
    gemm_kernel<<<nTiles, 256, 0, stream>>>(x, W, yA, n);
    int hopBlocks = (n + 3) / 4;   // 4 waves (nodes) per 256-thread block
    hop_kernel<false><<<hopBlocks, 256, 0, stream>>>(yA, yB, edges, off, dis, nullptr, n);
    hop_kernel<true><<<hopBlocks, 256, 0, stream>>>(yB, (float*)d_out, edges, off, dis, b, n);
}

// Round 4
// 264.233 us; speedup vs baseline: 1.7223x; 1.7223x over previous
//
#include <hip/hip_runtime.h>
#include <hip/hip_bf16.h>

#define IN_CH 128
#define OUT_CH 64

// ---------------- degree count (int4-vectorized) ----------------
__global__ void __launch_bounds__(256) count_kernel(const int* __restrict__ col,
                                                    int* __restrict__ cnt, int E) {
    int t = blockIdx.x * blockDim.x + threadIdx.x;
    int base = t * 4;
    if (base + 3 < E) {
        int4 c = *(const int4*)(col + base);
        atomicAdd(&cnt[c.x], 1);
        atomicAdd(&cnt[c.y], 1);
        atomicAdd(&cnt[c.z], 1);
        atomicAdd(&cnt[c.w], 1);
    } else {
        for (int i = base; i < E; ++i) atomicAdd(&cnt[col[i]], 1);
    }
}

// ---------------- 3-phase parallel exclusive scan ----------------
__global__ void __launch_bounds__(256) partial_kernel(const int* __restrict__ cnt,
                                                      int* __restrict__ bsum, int n) {
    __shared__ int red[256];
    int tid = threadIdx.x;
    int i = blockIdx.x * 256 + tid;
    red[tid] = (i < n) ? cnt[i] : 0;
    __syncthreads();
    for (int d = 128; d > 0; d >>= 1) {
        if (tid < d) red[tid] += red[tid + d];
        __syncthreads();
    }
    if (tid == 0) bsum[blockIdx.x] = red[0];
}

__global__ void __launch_bounds__(256) scansums_kernel(int* __restrict__ bsum, int nb) {
    __shared__ int ps[256];
    int tid = threadIdx.x;
    int v = (tid < nb) ? bsum[tid] : 0;
    ps[tid] = v;
    __syncthreads();
    for (int d = 1; d < 256; d <<= 1) {
        int t = 0;
        if (tid >= d) t = ps[tid - d];
        __syncthreads();
        if (tid >= d) ps[tid] += t;
        __syncthreads();
    }
    if (tid < nb) bsum[tid] = ps[tid] - v;   // exclusive
}

__global__ void __launch_bounds__(256) scanwrite_kernel(const int* __restrict__ cnt,
                                                        const int* __restrict__ bsum,
                                                        int* __restrict__ off,
                                                        int* __restrict__ pos,
                                                        float* __restrict__ dis, int n) {
    __shared__ int ps[256];
    int tid = threadIdx.x;
    int i = blockIdx.x * 256 + tid;
    int c = (i < n) ? cnt[i] : 0;
    ps[tid] = c;
    __syncthreads();
    for (int d = 1; d < 256; d <<= 1) {
        int t = 0;
        if (tid >= d) t = ps[tid - d];
        __syncthreads();
        if (tid >= d) ps[tid] += t;
        __syncthreads();
    }
    int excl = ps[tid] - c + bsum[blockIdx.x];
    if (i < n) {
        off[i] = excl;
        pos[i] = excl;
        dis[i] = rsqrtf((float)(c + 1));   // +1 self-loop, matches gcn_norm
        if (i == n - 1) off[n] = excl + c;
    }
}

// ---------------- scatter edges into CSR order, pack (row, norm) ----------------
__global__ void __launch_bounds__(256) scatter_kernel(const int* __restrict__ row,
                                                      const int* __restrict__ col,
                                                      const float* __restrict__ dis,
                                                      int* __restrict__ pos,
                                                      int2* __restrict__ edges, int E) {
    int t = blockIdx.x * blockDim.x + threadIdx.x;
    int base = t * 2;
    if (base + 1 < E) {
        int2 r = *(const int2*)(row + base);
        int2 c = *(const int2*)(col + base);
        float n0 = dis[r.x] * dis[c.x];
        float n1 = dis[r.y] * dis[c.y];
        int p0 = atomicAdd(&pos[c.x], 1);
        edges[p0] = make_int2(r.x, __float_as_int(n0));
        int p1 = atomicAdd(&pos[c.y], 1);
        edges[p1] = make_int2(r.y, __float_as_int(n1));
    } else if (base < E) {
        int r = row[base], c = col[base];
        int p = atomicAdd(&pos[c], 1);
        edges[p] = make_int2(r, __float_as_int(dis[r] * dis[c]));
    }
}

// ---------------- Y = X @ W^T : lane = output, W row pinned in 128 VGPRs ----------------
// W staged to LDS coalesced, then each lane pulls its row W[lane][0..127] into
// registers (pad 129 avoids bank conflicts). x-row address is wave-uniform
// (readfirstlane) -> broadcast/scalar loads. acc is 2 scalars -> no spills.
__global__ void __launch_bounds__(256, 2) gemm_kernel(const float* __restrict__ x,
                                                      const float* __restrict__ W,
                                                      float* __restrict__ y, int n) {
    __shared__ float Wl[OUT_CH * 129];
    for (int idx = threadIdx.x; idx < OUT_CH * IN_CH; idx += 256) {
        int o = idx >> 7, k = idx & 127;
        Wl[o * 129 + k] = W[idx];
    }
    __syncthreads();
    int lane = threadIdx.x & 63;
    float wreg[IN_CH];
#pragma unroll
    for (int j = 0; j < IN_CH / 4; ++j) {
        float4 t = *(const float4*)&Wl[lane * 129 + j * 4];
        wreg[4 * j] = t.x; wreg[4 * j + 1] = t.y;
        wreg[4 * j + 2] = t.z; wreg[4 * j + 3] = t.w;
    }
    int gw = (int)((blockIdx.x * 256 + threadIdx.x) >> 6);
    gw = __builtin_amdgcn_readfirstlane(gw);
    int nwaves = (gridDim.x * 256) >> 6;
    int nPairs = n >> 1;
    for (int p = gw; p < nPairs; p += nwaves) {
        const float* x0 = x + (size_t)(2 * p) * IN_CH;
        const float* x1 = x0 + IN_CH;
        float a0 = 0.f, a1 = 0.f;
#pragma unroll
        for (int k = 0; k < IN_CH; ++k) {
            a0 = fmaf(x0[k], wreg[k], a0);
            a1 = fmaf(x1[k], wreg[k], a1);
        }
        y[(size_t)(2 * p) * OUT_CH + lane] = a0;
        y[(size_t)(2 * p + 1) * OUT_CH + lane] = a1;
    }
    if ((n & 1) && gw == 0) {   // generic odd-n tail
        const float* x0 = x + (size_t)(n - 1) * IN_CH;
        float a0 = 0.f;
#pragma unroll
        for (int k = 0; k < IN_CH; ++k) a0 = fmaf(x0[k], wreg[k], a0);
        y[(size_t)(n - 1) * OUT_CH + lane] = a0;
    }
}

// ---------------- propagation hop: wave per node, 4 edges x float4 per issue ----------------
// lane = (grp in [0,4)) * 16 + (sub in [0,16)). grp = edge slot, sub = float4 chunk.
// One dwordx4 load serves 4 edges' rows; edge descriptors software-pipelined.
template <bool FINAL>
__global__ void __launch_bounds__(256) hop_kernel(const float* __restrict__ yin,
                                                  float* __restrict__ yout,
                                                  const int2* __restrict__ edges,
                                                  const int* __restrict__ off,
                                                  const float* __restrict__ dis,
                                                  const float* __restrict__ bias, int n) {
    int v = (int)((blockIdx.x * 256 + threadIdx.x) >> 6);
    if (v >= n) return;
    int lane = threadIdx.x & 63;
    int grp = lane >> 4;       // which edge within a quad
    int sub = lane & 15;       // which float4 chunk of the 64-float row
    int s = off[v], e = off[v + 1];
    float4 acc = make_float4(0.f, 0.f, 0.f, 0.f);
    if (grp == 0) {            // self-loop term, added once
        float dv = dis[v];
        float4 t = ((const float4*)(yin + (size_t)v * OUT_CH))[sub];
        float w = dv * dv;
        acc.x = w * t.x; acc.y = w * t.y; acc.z = w * t.z; acc.w = w * t.w;
    }
    int i = s + grp;
    bool have = (i < e);
    int2 ed = have ? edges[i] : make_int2(0, 0);
    while (have) {
        int j = i + 4;
        bool hnext = (j < e);
        int2 edn = hnext ? edges[j] : make_int2(0, 0);   // prefetch next descriptor
        float nrm = __int_as_float(ed.y);
        float4 t = ((const float4*)(yin + (size_t)ed.x * OUT_CH))[sub];
        acc.x = fmaf(nrm, t.x, acc.x);
        acc.y = fmaf(nrm, t.y, acc.y);
        acc.z = fmaf(nrm, t.z, acc.z);
        acc.w = fmaf(nrm, t.w, acc.w);
        ed = edn; i = j; have = hnext;
    }
    // reduce the 4 edge slots: lanes {sub, sub+16, sub+32, sub+48}
    acc.x += __shfl_xor(acc.x, 16, 64); acc.x += __shfl_xor(acc.x, 32, 64);
    acc.y += __shfl_xor(acc.y, 16, 64); acc.y += __shfl_xor(acc.y, 32, 64);
    acc.z += __shfl_xor(acc.z, 16, 64); acc.z += __shfl_xor(acc.z, 32, 64);
    acc.w += __shfl_xor(acc.w, 16, 64); acc.w += __shfl_xor(acc.w, 32, 64);
    if (grp == 0) {
        if (FINAL) {
            float4 bb = ((const float4*)bias)[sub];
            acc.x += bb.x; acc.y += bb.y; acc.z += bb.z; acc.w += bb.w;
        }
        ((float4*)(yout + (size_t)v * OUT_CH))[sub] = acc;
    }
}

extern "C" void kernel_launch(void* const* d_in, const int* in_sizes, int n_in,
                              void* d_out, int out_size, void* d_ws, size_t ws_size,
                              hipStream_t stream) {
    const float* x = (const float*)d_in[0];
    const int* ei = (const int*)d_in[1];
    const float* W = (const float*)d_in[2];
    const float* b = (const float*)d_in[3];
    int n = in_sizes[0] / IN_CH;   // 50000
    int E = in_sizes[1] / 2;       // 800000
    const int* row = ei;           // edge_index[0] = source
    const int* col = ei + E;       // edge_index[1] = target

    char* ws = (char*)d_ws;
    size_t o = 0;
    auto alloc = [&](size_t bytes) -> void* {
        void* p = ws + o;
        o += (bytes + 255) & ~(size_t)255;
        return p;
    };
    int*   cnt   = (int*)alloc((size_t)n * 4);
    int*   off   = (int*)alloc((size_t)(n + 1) * 4);
    int*   pos   = (int*)alloc((size_t)n * 4);
    float* dis   = (float*)alloc((size_t)n * 4);
    int2*  edges = (int2*)alloc((size_t)E * 8);
    float* yA    = (float*)alloc((size_t)n * OUT_CH * 4);
    float* yB    = (float*)alloc((size_t)n * OUT_CH * 4);
    int*   bsum  = (int*)alloc(1024 * 4);

    int nTiles = (n + 255) / 256;  // 196

    hipMemsetAsync(cnt, 0, (size_t)n * 4, stream);
    count_kernel<<<((E + 3) / 4 + 255) / 256, 256, 0, stream>>>(col, cnt, E);
    partial_kernel<<<nTiles, 256, 0, stream>>>(cnt, bsum, n);
    scansums_kernel<<<1, 256, 0, stream>>>(bsum, nTiles);
    scanwrite_kernel<<<nTiles, 256, 0, stream>>>(cnt, bsum, off, pos, dis, n);
    scatter_kernel<<<((E + 1) / 2 + 255) / 256, 256, 0, stream>>>(row, col, dis, pos, edges, E);
    gemm_kernel<<<784, 256, 0, stream>>>(x, W, yA, n);   // ~3 waves/SIMD, one generation
    int hopBlocks = (n + 3) / 4;   // wave per node
    hop_kernel<false><<<hopBlocks, 256, 0, stream>>>(yA, yB, edges, off, dis, nullptr, n);
    hop_kernel<true><<<hopBlocks, 256, 0, stream>>>(yB, (float*)d_out, edges, off, dis, b, n);
}